// Round 5
// baseline (4416.051 us; speedup 1.0000x reference)
//
#include <hip/hip_runtime.h>
#include <cstdint>
#include <cstddef>

// MultiLayerLSTM on gfx950 — round 9: direct-to-register fragment loads
// (no LDS staging at all; LDS only holds the cross-wave partial exchange)
// and all-to-all private-mailbox sync (no aggregator, one-hop signaling).
// 256 blocks (64/layer, 1 block/CU, LDS-forced). At round r, layer l does
// t = r - l. K-split: wave w owns K-slice [w*256,(w+1)*256) x all 4 gates
// x 16 units; A-fragments are loaded straight from L2/L3 into VGPRs
// (16B/lane), software-pipelined 4-deep against the MFMAs.
// Sync: block (l,b) owns sync row [own[64], in[64]]; producers scatter
// their step count into peers' rows (2 x 64-lane stores); consumers poll
// their own contiguous row (1 coalesced load + __all). h slabs publish via
// relaxed agent-scope (sc1 write-through) stores; readers use cached loads
// (each slab written once then read — no stale-L2 hazard; proven r7/r8).
// L=4 layers, B=64, T=256, D=H=1024.

#define LL 4
#define BB 64
#define TT 256
#define DD 1024
#define HH 1024
#define FOURH 4096
#define PPAD 68     // padded P row stride (f32): 2-way banks only (free)

typedef __bf16 bf16;
typedef __bf16 bf16x8 __attribute__((ext_vector_type(8)));
typedef __bf16 bf16x4 __attribute__((ext_vector_type(4)));
typedef __bf16 bf16x2 __attribute__((ext_vector_type(2)));
typedef float f32x4 __attribute__((ext_vector_type(4)));

__device__ __forceinline__ void async_load16(const void* g, void* l) {
    __builtin_amdgcn_global_load_lds(
        (const __attribute__((address_space(1))) unsigned int*)g,
        (__attribute__((address_space(3))) unsigned int*)l,
        16, 0, 0);
}

__device__ __forceinline__ f32x4 mfma_bf16(bf16x8 a, bf16x8 b, f32x4 c) {
    return __builtin_amdgcn_mfma_f32_16x16x32_bf16(a, b, c, 0, 0, 0);
}

__device__ __forceinline__ float fsig(float x) {
    return 1.f / (1.f + __expf(-x));
}
__device__ __forceinline__ float ftanh(float x) {
    x = fminf(10.f, fmaxf(-10.f, x));
    float e = __expf(2.f * x);
    return (e - 1.f) / (e + 1.f);
}

__device__ __forceinline__ int aload(const int* p) {
    return __hip_atomic_load(p, __ATOMIC_RELAXED, __HIP_MEMORY_SCOPE_AGENT);
}
__device__ __forceinline__ void astore(int* p, int v) {
    __hip_atomic_store(p, v, __ATOMIC_RELAXED, __HIP_MEMORY_SCOPE_AGENT);
}

// ---------------- f32 -> bf16 convert (vectorized x4) ----------------
__global__ void cvt_f32_bf16(const float* __restrict__ in, bf16* __restrict__ out, int n4) {
    int i = blockIdx.x * blockDim.x + threadIdx.x;
    if (i < n4) {
        float4 v = ((const float4*)in)[i];
        bf16x4 o = { (bf16)v.x, (bf16)v.y, (bf16)v.z, (bf16)v.w };
        ((bf16x4*)out)[i] = o;
    }
}

// x [B][T][D] f32 -> x_bf [T][B][D] bf16. One block per (b,t) row.
__global__ __launch_bounds__(256) void cvt_x_transpose(
    const float* __restrict__ x, bf16* __restrict__ out) {
    int bx = blockIdx.x;           // = b*TT + t
    int b = bx >> 8, t = bx & 255;
    int tid = threadIdx.x;
    float4 v = ((const float4*)(x + (size_t)bx * DD))[tid];
    bf16x4 o = { (bf16)v.x, (bf16)v.y, (bf16)v.z, (bf16)v.w };
    ((bf16x4*)(out + ((size_t)(t * BB + b)) * DD))[tid] = o;
}

// ---------------- GEMM: C[M,N] = A[M,K] @ W[N,K]^T + bias[N] ----------------
// REMAP: output row m = t*B+b is written to row b*TT+t (f32 logits in [B][T]).
template <bool OUT_BF16, bool REMAP>
__global__ __launch_bounds__(256) void gemm_bt(
    const bf16* __restrict__ A, const bf16* __restrict__ W,
    const float* __restrict__ bias, void* __restrict__ Cout,
    int M, int N, int K)
{
    __shared__ bf16 As[128 * 32];
    __shared__ bf16 Bs[128 * 32];
    const int tid = threadIdx.x;
    const int wave = tid >> 6, lane = tid & 63;
    const int lmod = lane & 15, lhalf = lane >> 4;
    const int m0 = blockIdx.y * 128, n0 = blockIdx.x * 128;
    const int wr = (wave >> 1) * 64, wc = (wave & 1) * 64;

    f32x4 acc[4][4] = {};

    const int arow = tid >> 2;
    const int acol = (tid & 3) * 8;
    const bf16* Ab  = A + (size_t)(m0 + arow) * K + acol;
    const bf16* Ab2 = A + (size_t)(m0 + 64 + arow) * K + acol;
    const bf16* Wb  = W + (size_t)(n0 + arow) * K + acol;
    const bf16* Wb2 = W + (size_t)(n0 + 64 + arow) * K + acol;

    for (int kc = 0; kc < K; kc += 32) {
        async_load16(Ab + kc,  &As[tid * 8]);
        async_load16(Ab2 + kc, &As[2048 + tid * 8]);
        async_load16(Wb + kc,  &Bs[tid * 8]);
        async_load16(Wb2 + kc, &Bs[2048 + tid * 8]);
        __syncthreads();

        bf16x8 af[4], bfr[4];
#pragma unroll
        for (int mt = 0; mt < 4; mt++)
            af[mt] = *(const bf16x8*)&As[(wr + mt * 16 + lmod) * 32 + lhalf * 8];
#pragma unroll
        for (int nt = 0; nt < 4; nt++)
            bfr[nt] = *(const bf16x8*)&Bs[(wc + nt * 16 + lmod) * 32 + lhalf * 8];
#pragma unroll
        for (int mt = 0; mt < 4; mt++)
#pragma unroll
            for (int nt = 0; nt < 4; nt++)
                acc[mt][nt] = mfma_bf16(af[mt], bfr[nt], acc[mt][nt]);
        __syncthreads();
    }

#pragma unroll
    for (int mt = 0; mt < 4; mt++) {
#pragma unroll
        for (int nt = 0; nt < 4; nt++) {
            int n = n0 + wc + nt * 16 + lmod;
            float bv = bias[n];
#pragma unroll
            for (int r = 0; r < 4; r++) {
                int m = m0 + wr + mt * 16 + lhalf * 4 + r;
                int orow = REMAP ? ((m & 63) * TT + (m >> 6)) : m;
                float v = acc[mt][nt][r] + bv;
                if (OUT_BF16)
                    ((bf16*)Cout)[(size_t)orow * N + n] = (bf16)v;
                else
                    ((float*)Cout)[(size_t)orow * N + n] = v;
            }
        }
    }
}

// ---------------- Pipelined persistent LSTM kernel (all layers) ----------------
// Per round t: [in-wait: poll own sync row .in >= t+1] -> B1 ->
// MFMA_in (direct pipelined global fragment loads) -> [own-wait: poll .own
// >= t, hidden under MFMA_in] -> B2 -> MFMA_own (direct loads, accumulate)
// -> P write -> B3 -> reduce 4 wave-partials + cell update + publish h (sc1)
// -> B4 (vmcnt drain) -> wave0 scatter-stores step count to all peers' .own
// slots and next layer's .in slots. Zero cache fences, zero LDS staging.
__global__ __launch_bounds__(256, 1) void lstm_pipe(
    const bf16* __restrict__ x_bf,     // [T*B, D] layer-0 input slabs
    const bf16* __restrict__ h0_all,   // [L, B*H] initial h (bf16)
    const float* __restrict__ c0_all,  // [L, B*H] initial c (f32)
    const bf16* __restrict__ wih,      // [L, 4H, H]
    const bf16* __restrict__ whh,      // [L, 4H, H]
    const float* __restrict__ bias,    // [L, 4H]
    bf16* __restrict__ hseq_base,      // [L, T*B, H]
    float* __restrict__ outH, float* __restrict__ outC,  // [L, B*H]
    int* __restrict__ sync)            // [256][2][64] ints, zeroed
{
    // P exchange only. Plane [4] is never touched: pads LDS to 87 KB so two
    // blocks cannot share a CU (forces the 1 block/CU co-residency the
    // pipeline's spin-waits assume).
    __shared__ float P[5][64][PPAD];
    float* Pf = &P[0][0][0];

    const int tid = threadIdx.x;
    const int wave = tid >> 6, lane = tid & 63;
    const int lmod = lane & 15, lhalf = lane >> 4;
    const int bid = blockIdx.x;
    const int layer = bid >> 6;
    const int blk = bid & 63;
    const int j0 = blk * 16;

    const size_t SLAB = (size_t)TT * BB * HH;
    const bf16* inseq = (layer == 0) ? x_bf : (hseq_base + (size_t)(layer - 1) * SLAB);
    bf16* hseq = hseq_base + (size_t)layer * SLAB;
    const bf16* h0 = h0_all + (size_t)layer * BB * HH;
    const float* c0 = c0_all + (size_t)layer * BB * HH;
    float* oH = outH + (size_t)layer * BB * HH;
    float* oC = outC + (size_t)layer * BB * HH;

    // sync rows: this block polls sync[bid][0][*] (.own) and sync[bid][1][*]
    // (.in, written by the previous layer). As producer it scatter-stores to
    // word (layer*64+lane)*128 + blk and ((layer+1)*64+lane)*128 + 64 + blk.
    int* myOwn = sync + bid * 128;
    int* myIn  = sync + bid * 128 + 64;
    int* peerOwnBase = sync + (size_t)(layer * 64) * 128 + blk;
    int* nextInBase  = sync + (size_t)((layer + 1) * 64) * 128 + 64 + blk; // layer<3 only

    // persistent weight fragments, K-split: wave's K-cols = wave*256 + kc*32
    // + lhalf*8; row = gate nt, unit j0+lmod.
    bf16x8 wI[4][8], wH[4][8];
    {
        const size_t lbase = (size_t)layer * FOURH;
#pragma unroll
        for (int nt = 0; nt < 4; nt++) {
            const bf16* rI = wih + (lbase + nt * 1024 + j0 + lmod) * 1024
                                 + wave * 256 + lhalf * 8;
            const bf16* rH = whh + (lbase + nt * 1024 + j0 + lmod) * 1024
                                 + wave * 256 + lhalf * 8;
#pragma unroll
            for (int kc = 0; kc < 8; kc++) {
                wI[nt][kc] = *(const bf16x8*)(rI + kc * 32);
                wH[nt][kc] = *(const bf16x8*)(rH + kc * 32);
            }
        }
    }

    // per-thread gate biases for the cell update (jj is q-invariant)
    const int jj0 = (tid * 2) & 15;
    float bj[4][2];
#pragma unroll
    for (int g = 0; g < 4; g++) {
        bj[g][0] = bias[layer * FOURH + g * 1024 + j0 + jj0];
        bj[g][1] = bias[layer * FOURH + g * 1024 + j0 + jj0 + 1];
    }

    // persistent cell state: thread owns (m, jj0) and (m, jj0+1) at p=q*512+tid*2
    float2 creg[2];
#pragma unroll
    for (int q = 0; q < 2; q++) {
        int p = q * 512 + tid * 2;
        creg[q] = *(const float2*)&c0[(p >> 4) * 1024 + j0 + (p & 15)];
    }

    // direct-to-register K-split matmul: 4 pipelined stages of 2 K-chunks.
    // Fragment (mt,kc) = slab[(mt*16+lmod)][wave*256 + kc*32 + lhalf*8 ..+8]
    // — identical data the LDS path delivered, minus the LDS round-trip.
    auto mmul = [&](const bf16* src, const bf16x8 (&W)[4][8], f32x4 (&acc)[4][4]) {
        const bf16* b[4];
#pragma unroll
        for (int mt = 0; mt < 4; mt++)
            b[mt] = src + (size_t)(mt * 16 + lmod) * 1024 + wave * 256 + lhalf * 8;
        bf16x8 fA[2][4], fB[2][4];
#pragma unroll
        for (int h = 0; h < 2; h++)
#pragma unroll
            for (int mt = 0; mt < 4; mt++)
                fA[h][mt] = *(const bf16x8*)(b[mt] + h * 32);
#pragma unroll
        for (int kp = 0; kp < 4; kp++) {
            if (kp < 3) {
#pragma unroll
                for (int h = 0; h < 2; h++)
#pragma unroll
                    for (int mt = 0; mt < 4; mt++)
                        fB[h][mt] = *(const bf16x8*)(b[mt] + ((kp + 1) * 2 + h) * 32);
            }
#pragma unroll
            for (int h = 0; h < 2; h++)
#pragma unroll
                for (int mt = 0; mt < 4; mt++)
#pragma unroll
                    for (int nt = 0; nt < 4; nt++)
                        acc[mt][nt] = mfma_bf16(fA[h][mt], W[nt][kp * 2 + h], acc[mt][nt]);
#pragma unroll
            for (int h = 0; h < 2; h++)
#pragma unroll
                for (int mt = 0; mt < 4; mt++)
                    fA[h][mt] = fB[h][mt];
        }
    };

    for (int t = 0; t < TT; t++) {
        // ---- in-wait: producers completed step t (stored t+1) ----
        if (layer > 0 && wave == 0) {
            for (;;) {
                int v = aload(&myIn[lane]);
                if (__all(v >= t + 1)) break;
            }
        }
        __syncthreads();                       // B1
        asm volatile("" ::: "memory");

        // ---- input projection: direct loads + MFMA, pipelined ----
        f32x4 acc[4][4] = {};
        mmul(inseq + (size_t)t * (BB * HH), wI, acc);

        // ---- own-wait (hidden under the input-side work above) ----
        if (t > 0 && wave == 0) {
            for (;;) {
                int v = aload(&myOwn[lane]);
                if (__all(v >= t)) break;
            }
        }
        __syncthreads();                       // B2
        asm volatile("" ::: "memory");

        // ---- recurrent matmul (accumulates onto input projection) ----
        mmul((t == 0) ? h0 : (hseq + (size_t)(t - 1) * BB * HH), wH, acc);

        // ---- park K-slice partials in P for the cross-wave reduction ----
#pragma unroll
        for (int mt = 0; mt < 4; mt++)
#pragma unroll
            for (int nt = 0; nt < 4; nt++)
#pragma unroll
                for (int rr = 0; rr < 4; rr++) {
                    int m = mt * 16 + lhalf * 4 + rr;
                    Pf[(wave * 64 + m) * PPAD + nt * 16 + lmod] = acc[mt][nt][rr];
                }
        __syncthreads();                       // B3

        // fused cell update (sum 4 wave-partials per gate); publish h via
        // sc1 write-through 4B stores
        const bool lastt = (t == TT - 1);
#pragma unroll
        for (int q = 0; q < 2; q++) {
            int p = q * 512 + tid * 2;
            int m = p >> 4, jj = p & 15;
            float gg4[4][2];
#pragma unroll
            for (int g = 0; g < 4; g++) {
                float s0 = bj[g][0], s1 = bj[g][1];
#pragma unroll
                for (int w = 0; w < 4; w++) {
                    float2 pv = *(const float2*)&Pf[(w * 64 + m) * PPAD + g * 16 + jj];
                    s0 += pv.x; s1 += pv.y;
                }
                gg4[g][0] = s0; gg4[g][1] = s1;
            }
            float cv[2], hv[2];
#pragma unroll
            for (int u = 0; u < 2; u++) {
                float gi = gg4[0][u], gf = gg4[1][u], gc = gg4[2][u], go = gg4[3][u];
                float cprev = u ? creg[q].y : creg[q].x;
                float c = fsig(gf) * cprev + fsig(gi) * ftanh(gc);
                float h = fsig(go) * ftanh(c);
                cv[u] = c; hv[u] = h;
            }
            creg[q].x = cv[0]; creg[q].y = cv[1];
            union { bf16x2 h2; unsigned int u32; } pk;
            pk.h2.x = (bf16)hv[0]; pk.h2.y = (bf16)hv[1];
            __hip_atomic_store(
                (unsigned int*)&hseq[((size_t)(t * BB + m)) * HH + j0 + jj],
                pk.u32, __ATOMIC_RELAXED, __HIP_MEMORY_SCOPE_AGENT);
            if (lastt) {
                *(float2*)&oH[m * 1024 + j0 + jj] = make_float2(hv[0], hv[1]);
                *(float2*)&oC[m * 1024 + j0 + jj] = make_float2(cv[0], cv[1]);
            }
        }

        // publish: B4's vmcnt(0) drain puts all h stores at the coherence
        // point; then wave0 scatter-signals all consumers in 2 instructions.
        __syncthreads();                       // B4
        if (wave == 0) {
            astore(peerOwnBase + (size_t)lane * 128, t + 1);
            if (layer < 3)
                astore(nextInBase + (size_t)lane * 128, t + 1);
        }
    }
}

extern "C" void kernel_launch(void* const* d_in, const int* in_sizes, int n_in,
                              void* d_out, int out_size, void* d_ws, size_t ws_size,
                              hipStream_t stream) {
    const float* x    = (const float*)d_in[0];
    const float* h0   = (const float*)d_in[1];
    const float* c0   = (const float*)d_in[2];
    const float* Wih  = (const float*)d_in[3];
    const float* Whh  = (const float*)d_in[4];
    const float* bias = (const float*)d_in[5];
    const float* Wout = (const float*)d_in[6];
    const float* bout = (const float*)d_in[7];

    // ---- workspace layout (~226.7 MB) ----
    char* p = (char*)d_ws;
    int*  sync    = (int*)p;  p += 256 * 128 * 4;                    // 128 KB sync rows
    bf16* x_bf    = (bf16*)p; p += (size_t)BB * TT * DD * 2;         // 32 MB ([T][B][D])
    bf16* hseq    = (bf16*)p; p += (size_t)LL * BB * TT * HH * 2;    // 128 MB (per-layer slabs)
    bf16* wih_bf  = (bf16*)p; p += (size_t)LL * FOURH * HH * 2;      // 32 MB
    bf16* whh_bf  = (bf16*)p; p += (size_t)LL * FOURH * HH * 2;      // 32 MB
    bf16* wout_bf = (bf16*)p; p += (size_t)DD * HH * 2;              // 2 MB
    bf16* h0_bf   = (bf16*)p; p += (size_t)LL * BB * HH * 2;         // 0.5 MB
    if ((size_t)(p - (char*)d_ws) > ws_size) return;

    hipMemsetAsync(sync, 0, 256 * 128 * 4, stream);

    // ---- convert inputs to bf16 ----
    cvt_x_transpose<<<BB * TT, 256, 0, stream>>>(x, x_bf);
    {
        struct { const float* in; bf16* out; size_t n; } jobs[4] = {
            { Wih,  wih_bf,  (size_t)LL * FOURH * HH },
            { Whh,  whh_bf,  (size_t)LL * FOURH * HH },
            { Wout, wout_bf, (size_t)DD * HH },
            { h0,   h0_bf,   (size_t)LL * BB * HH },
        };
        for (int j = 0; j < 4; j++) {
            int n4 = (int)(jobs[j].n / 4);
            cvt_f32_bf16<<<(n4 + 255) / 256, 256, 0, stream>>>(jobs[j].in, jobs[j].out, n4);
        }
    }

    float* logits = (float*)d_out;
    float* outH = logits + (size_t)BB * TT * DD;
    float* outC = outH + (size_t)LL * BB * HH;

    // ---- all 4 layers, pipelined, one persistent dispatch ----
    lstm_pipe<<<LL * 64, 256, 0, stream>>>(
        x_bf, h0_bf, c0, wih_bf, whh_bf, bias,
        hseq, outH, outC, sync);

    // ---- output projection from layer-3 hidden sequence ----
    dim3 g2(DD / 128, (BB * TT) / 128);
    gemm_bt<false, true><<<g2, 256, 0, stream>>>(
        hseq + (size_t)(LL - 1) * TT * BB * HH, wout_bf, bout, logits,
        BB * TT, DD, HH);
}